// Round 6
// baseline (1258.199 us; speedup 1.0000x reference)
//
#include <hip/hip_runtime.h>

typedef unsigned short u16;
typedef unsigned int u32;
typedef __attribute__((ext_vector_type(8))) __bf16 bf16x8;
typedef __attribute__((ext_vector_type(4))) float f32x4;

#define NSAMP 32768
#define HALF_LOG2PI 0.91893853320467274f

// ws u16 offsets
#define O_W1N 0
#define O_W2N 32768
#define O_MUW 65536
#define O_SGW 81920
#define O_ALW 98304
#define O_E1W 100352
#define O_E2W 108544
#define O_CORT 124928
#define CORT_STEP 262144   // 64 d * 64 j * 64 i u16 per step

// LDS byte offsets (52 KB)
#define L_TMP 0        // 8192: tmp [s][128B] bf16, XOR-swizzled
#define L_ENC 8192     // 16384: enc [s][256B] f32, 32B-granule XOR swizzle
#define L_H1A 24576    // phi/enc staging A (8KB)
#define L_H1B 32768    // staging B (8KB)
#define L_CLP 24576    // overlay: comp_lp [32][64] f32
#define L_ALP 32768    // overlay: alpha   [32][64] f32
#define L_H2  40960    // 8192: h2 bf16 [s][128B]
#define L_LM1 40960    // LSE overlays (H2 dead by LSE)
#define L_LM2 41984
#define L_LS1 43008
#define L_LS2 44032
#define L_XP  49152    // 4096: x bf16 [s][32k], 16B-granule XOR swizzle
#define LDS_BYTES 53248

static __device__ __forceinline__ u16 f2b(float x){ return __builtin_bit_cast(u16,(__bf16)x); }
static __device__ __forceinline__ float b2f(u16 u){ return __builtin_bit_cast(float,((u32)u)<<16); }
static __device__ __forceinline__ float b2flo(u32 v){ return __builtin_bit_cast(float, v<<16); }
static __device__ __forceinline__ float b2fhi(u32 v){ return __builtin_bit_cast(float, v & 0xffff0000u); }
static __device__ __forceinline__ u32 pk2(float lo, float hi){
  return (u32)__builtin_bit_cast(u16,(__bf16)lo) | ((u32)__builtin_bit_cast(u16,(__bf16)hi)<<16);
}
static __device__ __forceinline__ f32x4 MF(uint4 a, uint4 b, f32x4 c){
  union U{uint4 q; bf16x8 v;};
  U A, B; A.q=a; B.q=b;
  return __builtin_amdgcn_mfma_f32_16x16x32_bf16(A.v, B.v, c, 0, 0, 0);
}

// ---------------- prep: weights -> bf16 (k-contiguous rows) ----------------
__global__ void prep_w(const float* __restrict__ nw1, const float* __restrict__ nw2,
                       const float* __restrict__ muw, const float* __restrict__ sgw,
                       const float* __restrict__ alw, const float* __restrict__ e1w,
                       const float* __restrict__ e2w, u16* __restrict__ ws,
                       float* __restrict__ out) {
  int idx0 = blockIdx.x * blockDim.x + threadIdx.x;
  int stride = gridDim.x * blockDim.x;
  for (int idx = idx0; idx < 124928; idx += stride) {
    float v;
    if      (idx < 32768)  v = nw1[idx];
    else if (idx < 65536)  v = nw2[idx - 32768];
    else if (idx < 81920)  v = muw[idx - 65536];
    else if (idx < 98304)  v = sgw[idx - 81920];
    else if (idx < 100352) v = alw[idx - 98304];
    else if (idx < 108544) { int j = idx - 100352; int o = j >> 5, k = j & 31;
                             v = (k < 8) ? e1w[o*8 + k] : 0.0f; }
    else                   v = e2w[idx - 108544];
    ws[idx] = f2b(v);
  }
  if (idx0 == 0) out[NSAMP] = 0.0f;
}

// ---------------- prep: cores[t][i][d][j] -> coreJI[t][d][j][i] bf16 ----------------
__global__ void prep_core(const float* __restrict__ cores, u16* __restrict__ ws) {
  int t = blockIdx.x >> 6, d = blockIdx.x & 63;   // 960 blocks (t<15)
  __shared__ float T[64][65];
  for (int idx = threadIdx.x; idx < 4096; idx += 256) {
    int i = idx >> 6, j = idx & 63;
    T[i][j] = cores[((size_t)(t*64 + i)*64 + d)*64 + j];
  }
  __syncthreads();
  u16* dst = ws + O_CORT + (size_t)t*CORT_STEP + (size_t)d*4096;
  for (int idx = threadIdx.x; idx < 4096; idx += 256) {
    int j = idx >> 6, i = idx & 63;
    dst[j*64 + i] = f2b(T[i][j]);
  }
}

// ---------------- fused ----------------
__global__ __launch_bounds__(256, 2)
void fused(const float* __restrict__ X, const float* __restrict__ init_w,
           const float* __restrict__ b1e, const float* __restrict__ b2e,
           const float* __restrict__ b1n, const float* __restrict__ b2n,
           const float* __restrict__ mub, const float* __restrict__ sgb,
           const float* __restrict__ alb, const u16* __restrict__ ws,
           float* __restrict__ out) {
  __shared__ __align__(16) char Lp[LDS_BYTES];
  const int tid = threadIdx.x;
  const int w = tid >> 6, l = tid & 63, li = l & 15, g = l >> 4;
  const int e3 = li & 7;
  const int sw = e3 << 4;
  const int n0 = blockIdx.x * 64;
  float res = 0.f, nrm = 0.f;

  // init: tmp0 bf16 swizzled [s][r]; XP zero; norm0
  for (int idx = tid; idx < 4096; idx += 256) {
    int s = idx >> 6, r = idx & 63;
    *(u16*)(Lp + L_TMP + s*128 + ((2*r) ^ ((s & 7) << 4))) = f2b(init_w[r]);
  }
  { uint4 z = {0,0,0,0};
    *(uint4*)(Lp + L_XP + tid*16) = z; }
  if (tid < 64) { float v = init_w[tid]; nrm += 64.f * v * v; }
  __syncthreads();

  for (int t = 0; t < 16; ++t) {
    // ---- X load -> XP bf16 [s][32k] 16B-granule swizzled ----
    for (int idx = tid; idx < 512; idx += 256) {
      int d = idx >> 6, s = idx & 63;
      float x = X[(size_t)(n0 + s)*128 + d*16 + t];
      *(u16*)(Lp + L_XP + s*64 + ((2*d) ^ ((s & 3) << 4))) = f2b(x);
    }

    // ---- tmp fragments: load ONCE (phi h1 + update) ----
    uint4 Bq0[4], Bq1[4];
#pragma unroll
    for (int st = 0; st < 4; ++st) {
      int s = st*16 + li;
      Bq0[st] = *(const uint4*)(Lp + L_TMP + s*128 + ((16*g) ^ sw));
      Bq1[st] = *(const uint4*)(Lp + L_TMP + s*128 + ((64 + 16*g) ^ sw));
    }

    // ---- phi h1(512)->h2(64): 9-phase pipeline, weights prefetched 1 phase ahead ----
    f32x4 acc2[4];
#pragma unroll
    for (int st = 0; st < 4; ++st) acc2[st] = (f32x4){0.f,0.f,0.f,0.f};
    uint4 af0, af1, c0, c1;
    float4 bb;
    {
      const u16* a0p = ws + O_W1N + (w*16 + li)*64 + 8*g;
      af0 = *(const uint4*)a0p; af1 = *(const uint4*)(a0p + 32);
      bb  = *(const float4*)(b1n + w*16 + 4*g);
    }
#pragma unroll 1
    for (int p = 0; p <= 8; ++p) {
      uint4 nf0, nf1, nc0, nc1; float4 nbb;
      if (p < 7) {
        const u16* a0p = ws + O_W1N + ((p+1)*64 + w*16 + li)*64 + 8*g;
        nf0 = *(const uint4*)a0p; nf1 = *(const uint4*)(a0p + 32);
        nbb = *(const float4*)(b1n + (p+1)*64 + w*16 + 4*g);
      }
      if (p < 8) {
        const u16* a2p = ws + O_W2N + (w*16 + li)*512 + p*64 + 8*g;
        nc0 = *(const uint4*)a2p; nc1 = *(const uint4*)(a2p + 32);
      }
      if (p < 8) {
        char* H1b = Lp + ((p & 1) ? L_H1B : L_H1A);
#pragma unroll
        for (int st = 0; st < 4; ++st) {
          int s = st*16 + li;
          f32x4 a1 = (f32x4){0.f,0.f,0.f,0.f};
          a1 = MF(af0, Bq0[st], a1); a1 = MF(af1, Bq1[st], a1);
          float v0 = fmaxf(a1[0] + bb.x, 0.f), v1 = fmaxf(a1[1] + bb.y, 0.f);
          float v2 = fmaxf(a1[2] + bb.z, 0.f), v3 = fmaxf(a1[3] + bb.w, 0.f);
          *(u32*)(H1b + s*128 + ((32*w + 8*g) ^ sw))     = pk2(v0, v1);
          *(u32*)(H1b + s*128 + ((32*w + 8*g + 4) ^ sw)) = pk2(v2, v3);
        }
      }
      if (p > 0) {
        const char* H1r = Lp + (((p-1) & 1) ? L_H1B : L_H1A);
#pragma unroll
        for (int st = 0; st < 4; ++st) {
          int s = st*16 + li;
          uint4 b0 = *(const uint4*)(H1r + s*128 + ((16*g) ^ sw));
          uint4 b1 = *(const uint4*)(H1r + s*128 + ((64 + 16*g) ^ sw));
          acc2[st] = MF(c0, b0, acc2[st]); acc2[st] = MF(c1, b1, acc2[st]);
        }
      }
      __syncthreads();
      af0 = nf0; af1 = nf1; bb = nbb; c0 = nc0; c1 = nc1;
    }
    { // h2 epilogue -> H2 bf16 swizzled
      float4 b2 = *(const float4*)(b2n + w*16 + 4*g);
#pragma unroll
      for (int st = 0; st < 4; ++st) {
        int s = st*16 + li;
        float v0 = fmaxf(acc2[st][0] + b2.x, 0.f), v1 = fmaxf(acc2[st][1] + b2.y, 0.f);
        float v2 = fmaxf(acc2[st][2] + b2.z, 0.f), v3 = fmaxf(acc2[st][3] + b2.w, 0.f);
        *(u32*)(Lp + L_H2 + s*128 + ((32*w + 8*g) ^ sw))     = pk2(v0, v1);
        *(u32*)(Lp + L_H2 + s*128 + ((32*w + 8*g + 4) ^ sw)) = pk2(v2, v3);
      }
    }
    __syncthreads();

    // ---- hoist x values + alpha weights ----
    float xv[4][4];
#pragma unroll
    for (int st = 0; st < 4; ++st) {
      int s = st*16 + li;
      uint2 xq = *(const uint2*)(Lp + L_XP + s*64 + ((8*(g & 1)) ^ ((li & 3) << 4)));
      xv[st][0] = b2flo(xq.x); xv[st][1] = b2fhi(xq.x);
      xv[st][2] = b2flo(xq.y); xv[st][3] = b2fhi(xq.y);
    }
    uint4 aw[2][2];
#pragma unroll
    for (int ot = 0; ot < 2; ++ot) {
      const u16* aa = ws + O_ALW + (ot*16 + li)*64 + 8*g;
      aw[ot][0] = *(const uint4*)aa; aw[ot][1] = *(const uint4*)(aa + 32);
    }

    // ---- mu/sig -> comp_lp (weights prefetched 1 c ahead) ----
    uint4 sf0, sf1, mf0, mf1; float4 bs, bm;
    {
      const u16* as_ = ws + O_SGW + (w*16 + li)*64 + 8*g;
      const u16* am_ = ws + O_MUW + (w*16 + li)*64 + 8*g;
      sf0 = *(const uint4*)as_; sf1 = *(const uint4*)(as_ + 32);
      mf0 = *(const uint4*)am_; mf1 = *(const uint4*)(am_ + 32);
      bs = *(const float4*)(sgb + w*16 + 4*g);
      bm = *(const float4*)(mub + w*16 + 4*g);
    }
#pragma unroll 1
    for (int c = 0; c < 4; ++c) {
      uint4 ns0, ns1, nm0, nm1; float4 nbs, nbm;
      if (c < 3) {
        int ob = (c+1)*64 + w*16;
        const u16* as_ = ws + O_SGW + (ob + li)*64 + 8*g;
        const u16* am_ = ws + O_MUW + (ob + li)*64 + 8*g;
        ns0 = *(const uint4*)as_; ns1 = *(const uint4*)(as_ + 32);
        nm0 = *(const uint4*)am_; nm1 = *(const uint4*)(am_ + 32);
        nbs = *(const float4*)(sgb + ob + 4*g);
        nbm = *(const float4*)(mub + ob + 4*g);
      }
      const float bsv[4] = {bs.x,bs.y,bs.z,bs.w};
      const float bmv[4] = {bm.x,bm.y,bm.z,bm.w};
#pragma unroll
      for (int st = 0; st < 4; ++st) {
        int s = st*16 + li;
        uint4 b0 = *(const uint4*)(Lp + L_H2 + s*128 + ((16*g) ^ sw));
        uint4 b1 = *(const uint4*)(Lp + L_H2 + s*128 + ((64 + 16*g) ^ sw));
        f32x4 aS = (f32x4){0.f,0.f,0.f,0.f}, aM = (f32x4){0.f,0.f,0.f,0.f};
        aS = MF(sf0, b0, aS); aS = MF(sf1, b1, aS);
        aM = MF(mf0, b0, aM); aM = MF(mf1, b1, aM);
        float part = 0.f;
#pragma unroll
        for (int r = 0; r < 4; ++r) {
          float ls = aS[r] + bsv[r];
          float mu = aM[r] + bmv[r];
          float z = (xv[st][r] - mu) * __expf(-ls);
          part += -0.5f*z*z - ls - HALF_LOG2PI;
        }
        float comb = part + __shfl_xor(part, 16);
        if (!(g & 1)) {
          int mix = c*8 + 2*w + (g >> 1);
          *(float*)(Lp + L_CLP + (mix*64 + s)*4) = comb;
        }
      }
      sf0 = ns0; sf1 = ns1; mf0 = nm0; mf1 = nm1; bs = nbs; bm = nbm;
    }
    // ---- alpha logits -> ALP f32 ----
    {
      int s = w*16 + li;
      uint4 b0 = *(const uint4*)(Lp + L_H2 + s*128 + ((16*g) ^ sw));
      uint4 b1 = *(const uint4*)(Lp + L_H2 + s*128 + ((64 + 16*g) ^ sw));
#pragma unroll
      for (int ot = 0; ot < 2; ++ot) {
        f32x4 acc = (f32x4){0.f,0.f,0.f,0.f};
        acc = MF(aw[ot][0], b0, acc); acc = MF(aw[ot][1], b1, acc);
        float4 ab4 = *(const float4*)(alb + ot*16 + 4*g);
        const float abv[4] = {ab4.x, ab4.y, ab4.z, ab4.w};
#pragma unroll
        for (int r = 0; r < 4; ++r)
          *(float*)(Lp + L_ALP + ((ot*16 + 4*g + r)*64 + s)*4) = acc[r] + abv[r];
      }
    }
    __syncthreads();

    // ---- parallel LSE ----
    float g1, g2;
    {
      int s = l;
      float m1 = -1e30f, m2 = -1e30f;
#pragma unroll
      for (int mm = 0; mm < 8; ++mm) {
        int m = w*8 + mm;
        float a = *(const float*)(Lp + L_ALP + (m*64 + s)*4);
        float c = *(const float*)(Lp + L_CLP + (m*64 + s)*4);
        m1 = fmaxf(m1, a + c); m2 = fmaxf(m2, a);
      }
      *(float*)(Lp + L_LM1 + (w*64 + s)*4) = m1;
      *(float*)(Lp + L_LM2 + (w*64 + s)*4) = m2;
      __syncthreads();
      g1 = fmaxf(fmaxf(*(const float*)(Lp + L_LM1 + s*4),
                       *(const float*)(Lp + L_LM1 + (64 + s)*4)),
                 fmaxf(*(const float*)(Lp + L_LM1 + (128 + s)*4),
                       *(const float*)(Lp + L_LM1 + (192 + s)*4)));
      g2 = fmaxf(fmaxf(*(const float*)(Lp + L_LM2 + s*4),
                       *(const float*)(Lp + L_LM2 + (64 + s)*4)),
                 fmaxf(*(const float*)(Lp + L_LM2 + (128 + s)*4),
                       *(const float*)(Lp + L_LM2 + (192 + s)*4)));
      float s1 = 0.f, s2 = 0.f;
#pragma unroll
      for (int mm = 0; mm < 8; ++mm) {
        int m = w*8 + mm;
        float a = *(const float*)(Lp + L_ALP + (m*64 + s)*4);
        float c = *(const float*)(Lp + L_CLP + (m*64 + s)*4);
        s1 += __expf(a + c - g1); s2 += __expf(a - g2);
      }
      *(float*)(Lp + L_LS1 + (w*64 + s)*4) = s1;
      *(float*)(Lp + L_LS2 + (w*64 + s)*4) = s2;
      __syncthreads();
    }
    if (tid < 64) {
      float s1 = *(const float*)(Lp + L_LS1 + tid*4)
               + *(const float*)(Lp + L_LS1 + (64 + tid)*4)
               + *(const float*)(Lp + L_LS1 + (128 + tid)*4)
               + *(const float*)(Lp + L_LS1 + (192 + tid)*4);
      float s2 = *(const float*)(Lp + L_LS2 + tid*4)
               + *(const float*)(Lp + L_LS2 + (64 + tid)*4)
               + *(const float*)(Lp + L_LS2 + (128 + tid)*4)
               + *(const float*)(Lp + L_LS2 + (192 + tid)*4);
      res += (g1 + __logf(s1)) - (g2 + __logf(s2));
    }
    if (t == 15) break;
    __syncthreads();   // CLP/ALP reads done before encoder overwrites staging

    // ---- encoder: 5-phase pipeline, weights prefetched 1 phase ahead ----
    f32x4 acE[4];
#pragma unroll
    for (int st = 0; st < 4; ++st) acE[st] = (f32x4){0.f,0.f,0.f,0.f};
    uint4 ae, ce0, ce1; float4 be1;
    {
      const u16* aep = ws + O_E1W + (w*16 + li)*32 + 8*g;
      ae  = *(const uint4*)aep;
      be1 = *(const float4*)(b1e + w*16 + 4*g);
    }
#pragma unroll 1
    for (int p = 0; p <= 4; ++p) {
      uint4 nae, nc0, nc1; float4 nbb;
      if (p < 3) {
        const u16* aep = ws + O_E1W + ((p+1)*64 + w*16 + li)*32 + 8*g;
        nae = *(const uint4*)aep;
        nbb = *(const float4*)(b1e + (p+1)*64 + w*16 + 4*g);
      }
      if (p < 4) {
        const u16* c0p = ws + O_E2W + (w*16 + li)*256 + p*64 + 8*g;
        nc0 = *(const uint4*)c0p; nc1 = *(const uint4*)(c0p + 32);
      }
      if (p < 4) {
        char* H1b = Lp + ((p & 1) ? L_H1B : L_H1A);
#pragma unroll
        for (int st = 0; st < 4; ++st) {
          int s = st*16 + li;
          uint4 b0 = *(const uint4*)(Lp + L_XP + s*64 + ((16*g) ^ ((s & 3) << 4)));
          f32x4 ah = (f32x4){0.f,0.f,0.f,0.f};
          ah = MF(ae, b0, ah);
          float v0 = fmaxf(ah[0] + be1.x, 0.f), v1 = fmaxf(ah[1] + be1.y, 0.f);
          float v2 = fmaxf(ah[2] + be1.z, 0.f), v3 = fmaxf(ah[3] + be1.w, 0.f);
          *(u32*)(H1b + s*128 + ((32*w + 8*g) ^ sw))     = pk2(v0, v1);
          *(u32*)(H1b + s*128 + ((32*w + 8*g + 4) ^ sw)) = pk2(v2, v3);
        }
      }
      if (p > 0) {
        const char* H1r = Lp + (((p-1) & 1) ? L_H1B : L_H1A);
#pragma unroll
        for (int st = 0; st < 4; ++st) {
          int s = st*16 + li;
          uint4 b0 = *(const uint4*)(H1r + s*128 + ((16*g) ^ sw));
          uint4 b1 = *(const uint4*)(H1r + s*128 + ((64 + 16*g) ^ sw));
          acE[st] = MF(ce0, b0, acE[st]); acE[st] = MF(ce1, b1, acE[st]);
        }
      }
      if (p == 4) { // ENC epilogue: f32 [s][d], 32B-granule XOR swizzle
        float4 be = *(const float4*)(b2e + w*16 + 4*g);
        const float bev[4] = {be.x, be.y, be.z, be.w};
#pragma unroll
        for (int st = 0; st < 4; ++st) {
          int s = st*16 + li;
#pragma unroll
          for (int r = 0; r < 4; ++r) {
            int d = w*16 + 4*g + r;
            *(float*)(Lp + L_ENC + s*256 + ((((d >> 3) ^ e3)) << 5) + ((d & 7) << 2))
                = acE[st][r] + bev[r];
          }
        }
      }
      __syncthreads();
      ae = nae; be1 = nbb; ce0 = nc0; ce1 = nc1;
    }

    // ---- update: per-d MFMA, depth-4 A prefetch (slot = dd), E prefetch 1 dg ahead ----
    f32x4 acc[4];
#pragma unroll
    for (int st = 0; st < 4; ++st) acc[st] = (f32x4){0.f,0.f,0.f,0.f};
    const u16* AJ = ws + O_CORT + (size_t)t*CORT_STEP + (size_t)(w*16 + li)*64 + 8*g;
    uint4 As[4][2];
#pragma unroll
    for (int dd = 0; dd < 4; ++dd) {
      const u16* ap = AJ + (size_t)dd*4096;
      As[dd][0] = *(const uint4*)(ap);
      As[dd][1] = *(const uint4*)(ap + 32);
    }
    f32x4 E[4];
#pragma unroll
    for (int st = 0; st < 4; ++st)
      E[st] = *(const f32x4*)(Lp + L_ENC + (st*16 + li)*256 + (e3 << 5));
#pragma unroll 1
    for (int dg = 0; dg < 16; ++dg) {
      f32x4 En[4];
      if (dg < 15) {
#pragma unroll
        for (int st = 0; st < 4; ++st)
          En[st] = *(const f32x4*)(Lp + L_ENC + (st*16 + li)*256 +
                    ((((dg+1) >> 1) ^ e3) << 5) + (((dg+1) & 1) << 4));
      }
#pragma unroll
      for (int dd = 0; dd < 4; ++dd) {
        __builtin_amdgcn_s_setprio(1);
#pragma unroll
        for (int st = 0; st < 4; ++st) {
          f32x4 y = (f32x4){0.f,0.f,0.f,0.f};
          y = MF(As[dd][0], Bq0[st], y);
          y = MF(As[dd][1], Bq1[st], y);
          float e = E[st][dd];
          acc[st][0] += e * y[0]; acc[st][1] += e * y[1];
          acc[st][2] += e * y[2]; acc[st][3] += e * y[3];
        }
        __builtin_amdgcn_s_setprio(0);
        if (dg < 15) {
          const u16* ap = AJ + (size_t)(dg*4 + dd + 4)*4096;
          As[dd][0] = *(const uint4*)(ap);
          As[dd][1] = *(const uint4*)(ap + 32);
        }
      }
      if (dg < 15) {
#pragma unroll
        for (int st = 0; st < 4; ++st) E[st] = En[st];
      }
    }
    // epilogue: norm + write tmp_{t+1}
#pragma unroll
    for (int st = 0; st < 4; ++st) {
      int s = st*16 + li;
      nrm += acc[st][0]*acc[st][0] + acc[st][1]*acc[st][1]
           + acc[st][2]*acc[st][2] + acc[st][3]*acc[st][3];
      uint2 pv;
      pv.x = pk2(acc[st][0], acc[st][1]);
      pv.y = pk2(acc[st][2], acc[st][3]);
      *(uint2*)(Lp + L_TMP + s*128 + ((32*w + 8*g) ^ sw)) = pv;
    }
    __syncthreads();
  } // t loop

  if (tid < 64) out[n0 + tid] = res;

  __syncthreads();
  *(float*)(Lp + L_H1A + tid*4) = nrm;
  __syncthreads();
  if (tid < 64) {
    float v = *(const float*)(Lp + L_H1A + tid*4)
            + *(const float*)(Lp + L_H1A + (tid + 64)*4)
            + *(const float*)(Lp + L_H1A + (tid + 128)*4)
            + *(const float*)(Lp + L_H1A + (tid + 192)*4);
#pragma unroll
    for (int off = 32; off > 0; off >>= 1) v += __shfl_down(v, off);
    if (tid == 0) atomicAdd(out + NSAMP, v);
  }
}

extern "C" void kernel_launch(void* const* d_in, const int* in_sizes, int n_in,
                              void* d_out, int out_size, void* d_ws, size_t ws_size,
                              hipStream_t stream) {
  const float* X      = (const float*)d_in[0];
  const float* init_w = (const float*)d_in[1];
  const float* cores  = (const float*)d_in[2];
  const float* e1w    = (const float*)d_in[3];
  const float* b1e    = (const float*)d_in[4];
  const float* e2w    = (const float*)d_in[5];
  const float* b2e    = (const float*)d_in[6];
  const float* nw1    = (const float*)d_in[7];
  const float* b1n    = (const float*)d_in[8];
  const float* nw2    = (const float*)d_in[9];
  const float* b2n    = (const float*)d_in[10];
  const float* muw    = (const float*)d_in[11];
  const float* mub    = (const float*)d_in[12];
  const float* sgw    = (const float*)d_in[13];
  const float* sgb    = (const float*)d_in[14];
  const float* alw    = (const float*)d_in[15];
  const float* alb    = (const float*)d_in[16];
  float* out = (float*)d_out;
  u16*   ws  = (u16*)d_ws;

  prep_w<<<64, 256, 0, stream>>>(nw1, nw2, muw, sgw, alw, e1w, e2w, ws, out);
  prep_core<<<960, 256, 0, stream>>>(cores, ws);
  fused<<<NSAMP/64, 256, 0, stream>>>(X, init_w, b1e, b2e, b1n, b2n,
                                      mub, sgb, alb, ws, out);
}